// Round 1
// baseline (624.684 us; speedup 1.0000x reference)
//
#include <hip/hip_runtime.h>
#include <hip/hip_bf16.h>
#include <math.h>

#define TOK 4096
#define HD 1024
#define FD 4096
#define NE 8

typedef __attribute__((ext_vector_type(4))) float f32x4;
typedef __attribute__((ext_vector_type(8))) short s16x8;
typedef __attribute__((ext_vector_type(4))) unsigned short u16x4;

__device__ __forceinline__ unsigned short f2bf(float f) {
    union { float f; unsigned u; } v; v.f = f;
    unsigned r = v.u + 0x7FFFu + ((v.u >> 16) & 1u);   // RNE
    return (unsigned short)(r >> 16);
}

// ---------------- router: sigmoid(x@Wr+br), top-1, compact per-expert lists ----
__global__ void router_kernel(const float* __restrict__ x, const float* __restrict__ Wr,
                              const float* __restrict__ br, int* __restrict__ counts,
                              int* __restrict__ tlist, float* __restrict__ mprob) {
    const int lane = threadIdx.x & 63;
    const int t = blockIdx.x * 4 + (threadIdx.x >> 6);
    const float* xr = x + (size_t)t * HD;
    float acc[NE];
#pragma unroll
    for (int e = 0; e < NE; ++e) acc[e] = 0.f;
    for (int h = lane; h < HD; h += 64) {
        float xv = xr[h];
        f32x4 w0 = *(const f32x4*)(Wr + h * NE);
        f32x4 w1 = *(const f32x4*)(Wr + h * NE + 4);
        acc[0] += xv * w0.x; acc[1] += xv * w0.y; acc[2] += xv * w0.z; acc[3] += xv * w0.w;
        acc[4] += xv * w1.x; acc[5] += xv * w1.y; acc[6] += xv * w1.z; acc[7] += xv * w1.w;
    }
#pragma unroll
    for (int off = 32; off >= 1; off >>= 1)
#pragma unroll
        for (int e = 0; e < NE; ++e) acc[e] += __shfl_down(acc[e], off, 64);
    if (lane == 0) {
        float best = -1.f; int bi = 0;
#pragma unroll
        for (int e = 0; e < NE; ++e) {
            float r = 1.f / (1.f + expf(-(acc[e] + br[e])));
            if (r > best) { best = r; bi = e; }   // strict > keeps first index on tie
        }
        mprob[t] = best;
        int pos = atomicAdd(&counts[bi], 1);
        tlist[bi * TOK + pos] = t;
    }
}

// ---------------- gathered expert GEMM (128x128 tile, 16x16x32 bf16 MFMA) ------
// LDS layout: swizzled, row = M-or-N index (128 rows x 64 k-elems = 128B/row).
// element (r, k) lives at  r*64 + (((k>>3)+r)&7)*8 + (k&7)   (bf16 elems)
// -> conflict-free/2-way LDS access everywhere; B-stage writes ~4-way (cheap).
template<int KDIM, bool FC1>
__global__ __launch_bounds__(256, 2)
void expert_gemm(const float* __restrict__ Xf, const unsigned short* __restrict__ Ab,
                 const float* __restrict__ W, const int* __restrict__ counts,
                 const int* __restrict__ tlist, const float* __restrict__ mprob,
                 unsigned short* __restrict__ inter, float* __restrict__ out) {
    constexpr int NDIM = FC1 ? FD : HD;
    const int e = blockIdx.z;
    const int cnt = counts[e];
    const int m0 = blockIdx.y * 128;
    if (m0 >= cnt) return;
    const int n0 = blockIdx.x * 128;
    const float* We = W + (size_t)e * KDIM * NDIM;

    __shared__ unsigned short Al[128 * 64];
    __shared__ unsigned short Bl[128 * 64];
    __shared__ int s_tok[128];
    __shared__ float s_prob[128];

    const int tid = threadIdx.x;
    if (tid < 128) {
        int m = m0 + tid;
        int tk = (m < cnt) ? tlist[e * TOK + m] : -1;
        s_tok[tid] = tk;
        s_prob[tid] = (!FC1 && tk >= 0) ? mprob[tk] : 0.f;
    }
    __syncthreads();

    const int lane = tid & 63;
    const int wave = tid >> 6;
    const int wrow = (wave >> 1) << 6;
    const int wcol = (wave & 1) << 6;
    const int lm = lane & 15, quad = lane >> 4;

    f32x4 acc[4][4] = {};

    for (int k0 = 0; k0 < KDIM; k0 += 64) {
        // ---- stage A (gathered rows, ->bf16) ----
        if constexpr (FC1) {
#pragma unroll
            for (int it = 0; it < 8; ++it) {
                int q = tid + it * 256;       // 2048 float4 loads
                int m = q >> 4;
                int kk = (q & 15) << 2;
                int tk = s_tok[m];
                f32x4 v = {};
                if (tk >= 0) v = *(const f32x4*)(Xf + (size_t)tk * KDIM + (k0 + kk));
                u16x4 pv;
                pv.x = f2bf(v.x); pv.y = f2bf(v.y); pv.z = f2bf(v.z); pv.w = f2bf(v.w);
                int pos = (m << 6) + (((((kk >> 3) + m) & 7) << 3) | (kk & 7));
                *(u16x4*)&Al[pos] = pv;       // ds_write_b64, conflict-free
            }
        } else {
#pragma unroll
            for (int it = 0; it < 4; ++it) {
                int q = tid + it * 256;       // 1024 16B loads (already bf16)
                int m = q >> 3;
                int kg = q & 7;
                int tk = s_tok[m];
                s16x8 v = {};
                if (tk >= 0) v = *(const s16x8*)(Ab + (size_t)tk * KDIM + (k0 + (kg << 3)));
                int pos = (m << 6) + (((kg + m) & 7) << 3);
                *(s16x8*)&Al[pos] = v;        // ds_write_b128, conflict-free
            }
        }
        // ---- stage B (transpose k-major W -> [n][k], ->bf16) ----
        {
            int tg = tid >> 5;                // k-group of 8 rows
            int l32 = tid & 31;
#pragma unroll
            for (int nh = 0; nh < 4; ++nh) {
                int n = (nh << 5) + l32;
                const float* wp = We + (size_t)(k0 + (tg << 3)) * NDIM + (n0 + n);
                s16x8 bv;
#pragma unroll
                for (int kk = 0; kk < 8; ++kk)
                    bv[kk] = (short)f2bf(wp[kk * NDIM]);   // coalesced dword loads across lanes
                int pos = (n << 6) + (((tg + n) & 7) << 3);
                *(s16x8*)&Bl[pos] = bv;       // ds_write_b128, ~4-way
            }
        }
        __syncthreads();
        // ---- compute: 2 k-steps x 4x4 MFMA ----
#pragma unroll
        for (int kt = 0; kt < 2; ++kt) {
            s16x8 af[4], bf[4];
            int gk = (kt << 2) + quad;
#pragma unroll
            for (int mt = 0; mt < 4; ++mt) {
                int m = wrow + (mt << 4) + lm;
                af[mt] = *(const s16x8*)&Al[(m << 6) + (((gk + m) & 7) << 3)];
            }
#pragma unroll
            for (int nt = 0; nt < 4; ++nt) {
                int n = wcol + (nt << 4) + lm;
                bf[nt] = *(const s16x8*)&Bl[(n << 6) + (((gk + n) & 7) << 3)];
            }
#pragma unroll
            for (int mt = 0; mt < 4; ++mt)
#pragma unroll
                for (int nt = 0; nt < 4; ++nt)
                    acc[mt][nt] = __builtin_amdgcn_mfma_f32_16x16x32_bf16(
                        af[mt], bf[nt], acc[mt][nt], 0, 0, 0);
        }
        __syncthreads();
    }

    // ---- epilogue: C/D layout col=lane&15, row=quad*4+reg ----
#pragma unroll
    for (int mt = 0; mt < 4; ++mt) {
#pragma unroll
        for (int r = 0; r < 4; ++r) {
            int row = wrow + (mt << 4) + (quad << 2) + r;
            if (m0 + row >= cnt) continue;
            int tk = s_tok[row];
            int colb = n0 + wcol + lm;
            if constexpr (FC1) {
#pragma unroll
                for (int nt = 0; nt < 4; ++nt) {
                    float v = acc[mt][nt][r];
                    float g = 0.5f * v * (1.f + erff(v * 0.70710678f));  // exact gelu
                    inter[(size_t)tk * FD + colb + (nt << 4)] = f2bf(g);
                }
            } else {
                float p = s_prob[row];
#pragma unroll
                for (int nt = 0; nt < 4; ++nt)
                    out[(size_t)tk * HD + colb + (nt << 4)] = acc[mt][nt][r] * p;
            }
        }
    }
}

extern "C" void kernel_launch(void* const* d_in, const int* in_sizes, int n_in,
                              void* d_out, int out_size, void* d_ws, size_t ws_size,
                              hipStream_t stream) {
    const float* x  = (const float*)d_in[0];
    const float* Wr = (const float*)d_in[1];
    const float* br = (const float*)d_in[2];
    const float* W1 = (const float*)d_in[3];
    const float* W2 = (const float*)d_in[4];
    float* out = (float*)d_out;

    char* ws = (char*)d_ws;
    int* counts  = (int*)ws;                                   // 8 ints
    float* mprob = (float*)(ws + 256);                         // TOK floats (16 KB)
    int* tlist   = (int*)(ws + 256 + 16384);                   // NE*TOK ints (128 KB)
    unsigned short* inter = (unsigned short*)(ws + 256 + 16384 + 131072); // TOK*FD bf16 (32 MB)

    hipMemsetAsync(counts, 0, NE * sizeof(int), stream);
    router_kernel<<<TOK / 4, 256, 0, stream>>>(x, Wr, br, counts, tlist, mprob);
    // fc1: [cnt,1024] x [1024,4096] -> gelu -> bf16 inter
    expert_gemm<HD, true><<<dim3(FD / 128, TOK / 128, NE), 256, 0, stream>>>(
        x, nullptr, W1, counts, tlist, mprob, inter, nullptr);
    // fc2: [cnt,4096] x [4096,1024] -> *max_prob -> out
    expert_gemm<FD, false><<<dim3(HD / 128, TOK / 128, NE), 256, 0, stream>>>(
        nullptr, inter, W2, counts, tlist, mprob, nullptr, out);
}